// Round 1
// baseline (1502.044 us; speedup 1.0000x reference)
//
#include <hip/hip_runtime.h>
#include <math.h>

#define N_NB 32
#define O_DIM 2048
#define I_DIM 4096
#define E_DIM 3
#define D_DIM 8
#define H_DIM 16
#define SELF_W 0.7f
#define O_CHUNK 16

// ws layout: float w[32] at byte 0; unsigned bits[I_DIM] at byte 128.

__global__ void prep_kernel(const float* __restrict__ edge_feats,
                            const float* __restrict__ node_feats,
                            const float* __restrict__ W1e, const float* __restrict__ b1e,
                            const float* __restrict__ W2e, const float* __restrict__ b2e,
                            const float* __restrict__ W1n, const float* __restrict__ b1n,
                            const float* __restrict__ W2n, const float* __restrict__ b2n,
                            const int* __restrict__ neighbor_masks,
                            float* __restrict__ ws_w, unsigned* __restrict__ ws_bits) {
    const int blk = blockIdx.x;
    const int lane = threadIdx.x;
    if (blk < 64) {
        // pack neighbor_masks column i into a 32-bit bitmask
        const int i = blk * 64 + lane;
        unsigned bits = 0u;
        #pragma unroll
        for (int n = 0; n < N_NB; ++n)
            bits |= ((unsigned)(neighbor_masks[n * I_DIM + i] & 1)) << n;
        ws_bits[i] = bits;
    } else {
        // attention weights: both 32-lane halves of the wave compute duplicates
        const int n = lane & 31;
        // edge MLP
        float ef0 = edge_feats[n * E_DIM + 0];
        float ef1 = edge_feats[n * E_DIM + 1];
        float ef2 = edge_feats[n * E_DIM + 2];
        float elogit = b2e[0];
        #pragma unroll
        for (int h = 0; h < H_DIM; ++h) {
            float t = b1e[h] + ef0 * W1e[0 * H_DIM + h]
                             + ef1 * W1e[1 * H_DIM + h]
                             + ef2 * W1e[2 * H_DIM + h];
            elogit += tanhf(t) * W2e[h];
        }
        float escore = 1.0f / (1.0f + expf(-elogit));
        // node MLP
        float nf[D_DIM];
        #pragma unroll
        for (int d = 0; d < D_DIM; ++d) nf[d] = node_feats[n * D_DIM + d];
        float nlogit = b2n[0];
        #pragma unroll
        for (int h = 0; h < H_DIM; ++h) {
            float t = b1n[h];
            #pragma unroll
            for (int d = 0; d < D_DIM; ++d) t += nf[d] * W1n[d * H_DIM + h];
            nlogit += tanhf(t) * W2n[h];
        }
        float ncond = 1.0f / (1.0f + expf(-nlogit));
        float s = escore * ncond;
        // softmax over the 32 lanes
        float m = s;
        #pragma unroll
        for (int off = 1; off < 32; off <<= 1) m = fmaxf(m, __shfl_xor(m, off, 32));
        float p = expf(s - m);
        float sum = p;
        #pragma unroll
        for (int off = 1; off < 32; off <<= 1) sum += __shfl_xor(sum, off, 32);
        float wv = (1.0f - SELF_W) * p / sum;
        if (lane < 32) ws_w[n] = wv;
    }
}

__global__ __launch_bounds__(256) void bias_kernel(const float* __restrict__ target_b,
                                                   const float* __restrict__ neighbor_b,
                                                   const float* __restrict__ ws_w,
                                                   float* __restrict__ out_b) {
    __shared__ float wsh[N_NB];
    if (threadIdx.x < N_NB) wsh[threadIdx.x] = ws_w[threadIdx.x];
    __syncthreads();
    const int o = blockIdx.x * 256 + threadIdx.x;
    float acc = SELF_W * target_b[o];
    #pragma unroll
    for (int n = 0; n < N_NB; ++n)
        acc = fmaf(wsh[n], neighbor_b[n * O_DIM + o], acc);
    out_b[o] = acc;
}

__global__ __launch_bounds__(256) void main_kernel(const float* __restrict__ target_W,
                                                   const float* __restrict__ neighbor_W,
                                                   const int* __restrict__ target_mask,
                                                   const float* __restrict__ ws_w,
                                                   const unsigned* __restrict__ ws_bits,
                                                   float* __restrict__ out_W) {
    __shared__ float wsh[N_NB];
    if (threadIdx.x < N_NB) wsh[threadIdx.x] = ws_w[threadIdx.x];
    __syncthreads();

    const int i0 = blockIdx.x * 1024 + threadIdx.x * 4;   // 4 consecutive columns
    const int o0 = blockIdx.y * O_CHUNK;

    const uint4 bits = *(const uint4*)(ws_bits + i0);
    const int4 tmi = *(const int4*)(target_mask + i0);
    float tmf[4] = {(float)tmi.x, (float)tmi.y, (float)tmi.z, (float)tmi.w};

    // norm[i] = 1e-8 + 0.7*tm[i] + sum_n w[n]*nm[n,i]
    float nrm[4];
    #pragma unroll
    for (int c = 0; c < 4; ++c) nrm[c] = 1e-8f + SELF_W * tmf[c];
    #pragma unroll
    for (int n = 0; n < N_NB; ++n) {
        const float wn = wsh[n];
        nrm[0] += ((bits.x >> n) & 1) ? wn : 0.0f;
        nrm[1] += ((bits.y >> n) & 1) ? wn : 0.0f;
        nrm[2] += ((bits.z >> n) & 1) ? wn : 0.0f;
        nrm[3] += ((bits.w >> n) & 1) ? wn : 0.0f;
    }
    float inv[4];
    #pragma unroll
    for (int c = 0; c < 4; ++c) inv[c] = 1.0f / nrm[c];

    const size_t OI = (size_t)O_DIM * (size_t)I_DIM;
    for (int oo = 0; oo < O_CHUNK; ++oo) {
        const int o = o0 + oo;
        const size_t base = (size_t)o * I_DIM + (size_t)i0;
        const float4 tw = *(const float4*)(target_W + base);
        float a0 = SELF_W * tmf[0] * tw.x;
        float a1 = SELF_W * tmf[1] * tw.y;
        float a2 = SELF_W * tmf[2] * tw.z;
        float a3 = SELF_W * tmf[3] * tw.w;
        #pragma unroll
        for (int n = 0; n < N_NB; ++n) {
            const float4 v = *(const float4*)(neighbor_W + n * OI + base);
            const float wn = wsh[n];
            a0 = fmaf(((bits.x >> n) & 1) ? wn : 0.0f, v.x, a0);
            a1 = fmaf(((bits.y >> n) & 1) ? wn : 0.0f, v.y, a1);
            a2 = fmaf(((bits.z >> n) & 1) ? wn : 0.0f, v.z, a2);
            a3 = fmaf(((bits.w >> n) & 1) ? wn : 0.0f, v.w, a3);
        }
        float4 r;
        r.x = a0 * inv[0];
        r.y = a1 * inv[1];
        r.z = a2 * inv[2];
        r.w = a3 * inv[3];
        *(float4*)(out_W + base) = r;
    }
}

extern "C" void kernel_launch(void* const* d_in, const int* in_sizes, int n_in,
                              void* d_out, int out_size, void* d_ws, size_t ws_size,
                              hipStream_t stream) {
    const float* edge_feats     = (const float*)d_in[0];
    const float* node_feats     = (const float*)d_in[1];
    const float* W1e            = (const float*)d_in[2];
    const float* b1e            = (const float*)d_in[3];
    const float* W2e            = (const float*)d_in[4];
    const float* b2e            = (const float*)d_in[5];
    const float* W1n            = (const float*)d_in[6];
    const float* b1n            = (const float*)d_in[7];
    const float* W2n            = (const float*)d_in[8];
    const float* b2n            = (const float*)d_in[9];
    const float* target_W       = (const float*)d_in[10];
    const float* neighbor_W     = (const float*)d_in[11];
    const float* target_b       = (const float*)d_in[12];
    const float* neighbor_b     = (const float*)d_in[13];
    const int*   target_mask    = (const int*)d_in[14];
    const int*   neighbor_masks = (const int*)d_in[15];

    float*    out    = (float*)d_out;
    float*    ws_w   = (float*)d_ws;
    unsigned* ws_bits = (unsigned*)((char*)d_ws + 128);

    prep_kernel<<<65, 64, 0, stream>>>(edge_feats, node_feats, W1e, b1e, W2e, b2e,
                                       W1n, b1n, W2n, b2n, neighbor_masks, ws_w, ws_bits);
    bias_kernel<<<O_DIM / 256, 256, 0, stream>>>(target_b, neighbor_b, ws_w,
                                                 out + (size_t)O_DIM * I_DIM);
    main_kernel<<<dim3(I_DIM / 1024, O_DIM / O_CHUNK), 256, 0, stream>>>(
        target_W, neighbor_W, target_mask, ws_w, ws_bits, out);
}